// Round 8
// baseline (91.514 us; speedup 1.0000x reference)
//
#include <hip/hip_runtime.h>
#include <math.h>

#define WS 21
#define KWIN 43            // 2*WS+1
#define H 128
#define W 128
#define B 2
#define C 3
#define HW (H * W)
#define CHW (C * H * W)
#define NPIX (B * H * W)   // 32768
#define SIGMA_SPACE (1.0f / 98.0f)
#define NSPLIT 16
#define EXT 170            // W + 2*WS
#define SQ_THR_FP16 0.17f  // fp16-screen threshold: 0.15 + margin for half rounding
// wr * d^0.8 = exp2(0.8*log2(d) - 50*log2(e)*sq); 50*log2(e) = 72.13475204
#define NEG_SC_LOG2E 72.1347520445f
#define SG 17.509290f      // sum_{k=-21..21} exp(-k^2/98), fp64-derived

typedef _Float16 h2_t __attribute__((ext_vector_type(2)));

__device__ __forceinline__ int reflect_idx(int t, int n) {
    if (t < 0) t = -t;
    if (t > n - 1) t = 2 * (n - 1) - t;
    return t;
}

// ---------------- K1: H-pass conv (256 thr) + Sobel mask (128 thr) + out zero ----------------
__global__ __launch_bounds__(384)
void prep_kernel(const float* __restrict__ orig,
                 const float* __restrict__ smooth,
                 float* __restrict__ Gh, float* __restrict__ Qh,
                 float* __restrict__ mask, float* __restrict__ out) {
    __shared__ float row[EXT], rsq[EXT], wt[KWIN];
    const int bid = blockIdx.x;      // bc*128 + h ; bc = b*3+c
    const int h   = bid & 127;
    const int bc  = bid >> 7;
    const int t   = threadIdx.x;
    if (bid == 0 && t == 0) out[0] = 0.f;
    if (t < KWIN) { int k = t - WS; wt[t] = __expf(-SIGMA_SPACE * (float)(k * k)); }
    const float* src = smooth + bc * HW + h * W;
    if (t < EXT) {
        float v = src[reflect_idx(t - WS, W)];
        row[t] = v; rsq[t] = v * v;
    }
    __syncthreads();
    if (t < 256) {
        const int w = t & 127;
        const float* buf = (t < 128) ? row : rsq;
        float acc = 0.f;
#pragma unroll
        for (int y = 0; y < KWIN; ++y) acc = fmaf(wt[y], buf[w + y], acc);
        ((t < 128) ? Gh : Qh)[bid * W + w] = acc;
    } else if (bc == 0 || bc == 3) {
        const int b = bc / 3;
        const int w = t - 256;
        const float* ob = orig   + b * CHW;
        const float* sb = smooth + b * CHW;
        int hm = reflect_idx(h - 1, H), hp = reflect_idx(h + 1, H);
        int wm = reflect_idx(w - 1, W), wp = reflect_idx(w + 1, W);
        float eo = 0.f, es = 0.f;
#pragma unroll
        for (int c = 0; c < C; ++c) {
            const float* po = ob + c * HW;
            const float* ps = sb + c * HW;
            {
                float a00 = po[hm * W + wm], a01 = po[hm * W + w], a02 = po[hm * W + wp];
                float a10 = po[h  * W + wm],                        a12 = po[h  * W + wp];
                float a20 = po[hp * W + wm], a21 = po[hp * W + w], a22 = po[hp * W + wp];
                float gx = (a02 - a00) + 2.f * (a12 - a10) + (a22 - a20);
                float gy = (a20 - a00) + 2.f * (a21 - a01) + (a22 - a02);
                eo += sqrtf(gx * gx + gy * gy);
            }
            {
                float a00 = ps[hm * W + wm], a01 = ps[hm * W + w], a02 = ps[hm * W + wp];
                float a10 = ps[h  * W + wm],                        a12 = ps[h  * W + wp];
                float a20 = ps[hp * W + wm], a21 = ps[hp * W + w], a22 = ps[hp * W + wp];
                float gx = (a02 - a00) + 2.f * (a12 - a10) + (a22 - a20);
                float gy = (a20 - a00) + 2.f * (a21 - a01) + (a22 - a02);
                es += sqrtf(gx * gx + gy * gy);
            }
        }
        float m = ((eo < 20.0f) && ((es - eo) > 10.0f)) ? 1.0f : 0.0f;
        mask[(b << 14) + (h << 7) + w] = m;
    }
}

// ---- K2: fp16 screen + fused AL; survivors processed FROM LDS (no global gathers) ----
__global__ __launch_bounds__(256, 4)
void smooth_loss_kernel(const float* __restrict__ orig,
                        const float* __restrict__ smooth,
                        const float* __restrict__ Gh, const float* __restrict__ Qh,
                        const float* __restrict__ mask,
                        float* __restrict__ out) {
    __shared__ uint2 oA[340];       // fp16 (o0,o1),(o2,0); reflection pre-applied
    __shared__ uint2 sA[340];       // fp16 (s0,s1),(s2,0)
    __shared__ float red[4];

    const int t     = threadIdx.x;
    const int split = blockIdx.x & 15;
    const int rp    = (blockIdx.x >> 4) & 63;
    const int b     = blockIdx.x >> 10;
    const int h0    = rp * 2;
    const int w     = t & 127;
    const int half  = t >> 7;
    const int h     = h0 + half;
    const int lane  = t & 63;
    const int wave  = t >> 6;

    const float* ob  = orig   + b * CHW;
    const float* sb  = smooth + b * CHW;
    const float* GhB = Gh + b * 3 * HW;
    const float* QhB = Qh + b * 3 * HW;

    const int pix = (b << 14) + (h << 7) + w;
    const float m = mask[pix];
    const float thr_l = (m == 0.0f) ? SQ_THR_FP16 : -1.0f;   // m==1 lanes never set bits

    float o0c, o1c, o2c, s0c, s1c, s2c;
    {
        int hw = h * W + w;
        o0c = ob[hw]; o1c = ob[HW + hw]; o2c = ob[2 * HW + hw];
        s0c = sb[hw]; s1c = sb[HW + hw]; s2c = sb[2 * HW + hw];
    }
    const h2_t c01h = { (_Float16)o0c, (_Float16)o1c };
    const h2_t c2xh = { (_Float16)o2c, (_Float16)0.f };

    // AL constants (separable-Gaussian identity): per-channel s^2*Sg - 2s*Gh + Qh
    const float n0 = s0c * s0c * SG, n1 = s1c * s1c * SG, n2 = s2c * s2c * SG;
    const float tc0 = -2.f * s0c, tc1 = -2.f * s1c, tc2 = -2.f * s2c;

    // staging descriptors: element-1 = idx t, element-2 = idx t+256 (t<84); idx = r*170+e
    const int  e1r  = (t >= 170);
    const int  sc1  = reflect_idx((t - e1r * 170) - WS, W);
    const bool has2 = (t < 84);
    const int  sc2  = reflect_idx(t + 65, W);     // (t+256)-170-WS = t+65

    float accAL = 0.f, accS = 0.f;
    const int cb = half * EXT + w;

    for (int xi = split; xi < KWIN; xi += NSPLIT) {
        const int x   = xi - WS;
        const int hh0 = reflect_idx(h0 + x, H);
        const int hh1 = reflect_idx(h0 + 1 + x, H);
        const int rr  = half ? hh1 : hh0;          // reflect(h + x)

        __syncthreads();                   // previous iteration done reading LDS
        // staging loads: orig AND smooth rows, packed to fp16
        const int rowA = (e1r ? hh1 : hh0) * W;
        const float* pAo = ob + rowA + sc1;
        const float* pAs = sb + rowA + sc1;
        float ao0 = pAo[0], ao1 = pAo[HW], ao2 = pAo[2 * HW];
        float as0 = pAs[0], as1 = pAs[HW], as2 = pAs[2 * HW];
        float bo0 = 0.f, bo1 = 0.f, bo2 = 0.f, bs0 = 0.f, bs1 = 0.f, bs2 = 0.f;
        if (has2) {
            const float* pBo = ob + hh1 * W + sc2;
            const float* pBs = sb + hh1 * W + sc2;
            bo0 = pBo[0]; bo1 = pBo[HW]; bo2 = pBo[2 * HW];
            bs0 = pBs[0]; bs1 = pBs[HW]; bs2 = pBs[2 * HW];
        }
        // fused AL loads for this thread's own pixel at this xi
        const int ga = rr * W + w;
        float G0 = GhB[ga], G1 = GhB[HW + ga], G2 = GhB[2 * HW + ga];
        float Q0 = QhB[ga], Q1 = QhB[HW + ga], Q2 = QhB[2 * HW + ga];

        {
            h2_t v01 = { (_Float16)ao0, (_Float16)ao1 };
            h2_t v2x = { (_Float16)ao2, (_Float16)0.f };
            oA[t] = make_uint2(__builtin_bit_cast(unsigned, v01),
                               __builtin_bit_cast(unsigned, v2x));
            h2_t u01 = { (_Float16)as0, (_Float16)as1 };
            h2_t u2x = { (_Float16)as2, (_Float16)0.f };
            sA[t] = make_uint2(__builtin_bit_cast(unsigned, u01),
                               __builtin_bit_cast(unsigned, u2x));
            if (has2) {
                h2_t w01 = { (_Float16)bo0, (_Float16)bo1 };
                h2_t w2x = { (_Float16)bo2, (_Float16)0.f };
                oA[t + 256] = make_uint2(__builtin_bit_cast(unsigned, w01),
                                         __builtin_bit_cast(unsigned, w2x));
                h2_t y01 = { (_Float16)bs0, (_Float16)bs1 };
                h2_t y2x = { (_Float16)bs2, (_Float16)0.f };
                sA[t + 256] = make_uint2(__builtin_bit_cast(unsigned, y01),
                                         __builtin_bit_cast(unsigned, y2x));
            }
        }

        float xf = (float)x;
        float wtx = __expf(-SIGMA_SPACE * xf * xf);
        float gsum = (n0 + fmaf(tc0, G0, Q0))
                   + (n1 + fmaf(tc1, G1, Q1))
                   + (n2 + fmaf(tc2, G2, Q2));
        accAL = fmaf(wtx, gsum, accAL);
        __syncthreads();                   // staging visible

        // ---- branchless fp16 screen: survivor bits in two scalar regs ----
        unsigned mA = 0u, mB_ = 0u;
#pragma unroll
        for (int yi = 0; yi < KWIN; ++yi) {
            uint2 vv = oA[cb + yi];
            h2_t a01 = __builtin_bit_cast(h2_t, vv.x);
            h2_t a2x = __builtin_bit_cast(h2_t, vv.y);
            h2_t d01 = c01h - a01;
            h2_t d2x = c2xh - a2x;
            float sq = __builtin_amdgcn_fdot2(d01, d01,
                        __builtin_amdgcn_fdot2(d2x, d2x, 0.f, false), false);
            unsigned bit = (sq < thr_l) ? 1u : 0u;
            if (yi < 21) mA  = (mA  << 1) | bit;   // bit (20-yi)
            else         mB_ = (mB_ << 1) | bit;   // bit (42-yi)
        }
        // self-pair (xi=WS, yi=WS): term is exactly 0 (safe_pow(0)=0) -> drop the
        // guaranteed all-lanes survivor iteration
        if (xi == WS) mB_ &= ~(1u << 21);

        // ---- immediate consumption: survivors recomputed FROM LDS (fp16 data) ----
        unsigned mAll;
        while ((mAll = (mA | mB_)) != 0u) {
            int yi;
            if (mA) { int p = __builtin_ctz(mA); mA &= mA - 1; yi = 20 - p; }
            else    { int p = __builtin_ctz(mB_); mB_ &= mB_ - 1; yi = 42 - p; }
            uint2 ov = oA[cb + yi];         // divergent ds_read_b64 x2 (banks spread)
            uint2 sv = sA[cb + yi];
            h2_t a01 = __builtin_bit_cast(h2_t, ov.x);
            h2_t a2x = __builtin_bit_cast(h2_t, ov.y);
            h2_t d01 = c01h - a01;
            h2_t d2x = c2xh - a2x;
            float sq = __builtin_amdgcn_fdot2(d01, d01,
                        __builtin_amdgcn_fdot2(d2x, d2x, 0.f, false), false);
            float tt = -NEG_SC_LOG2E * sq;
            h2_t u01 = __builtin_bit_cast(h2_t, sv.x);
            h2_t u2x = __builtin_bit_cast(h2_t, sv.y);
            float d0 = fabsf(s0c - (float)u01.x);
            float d1 = fabsf(s1c - (float)u01.y);
            float d2 = fabsf(s2c - (float)u2x.x);
            accS += __builtin_amdgcn_exp2f(fmaf(0.8f, __builtin_amdgcn_logf(d0), tt))
                  + __builtin_amdgcn_exp2f(fmaf(0.8f, __builtin_amdgcn_logf(d1), tt))
                  + __builtin_amdgcn_exp2f(fmaf(0.8f, __builtin_amdgcn_logf(d2), tt));
        }
    }

    float r = m * accAL + accS;
#pragma unroll
    for (int off = 32; off > 0; off >>= 1) r += __shfl_down(r, off, 64);
    if (lane == 0) red[wave] = r;
    __syncthreads();
    if (t == 0) atomicAdd(out, (red[0] + red[1] + red[2] + red[3]) * (1.0f / (float)NPIX));
}

extern "C" void kernel_launch(void* const* d_in, const int* in_sizes, int n_in,
                              void* d_out, int out_size, void* d_ws, size_t ws_size,
                              hipStream_t stream) {
    const float* orig   = (const float*)d_in[0];
    const float* smooth = (const float*)d_in[1];
    float* out = (float*)d_out;

    float* Gh  = (float*)d_ws;                   // 98304 floats
    float* Qh  = Gh + B * C * HW;                // 98304 floats
    float* msk = Qh + B * C * HW;                // 32768 floats

    prep_kernel<<<B * C * H, 384, 0, stream>>>(orig, smooth, Gh, Qh, msk, out);
    smooth_loss_kernel<<<B * (H / 2) * NSPLIT, 256, 0, stream>>>(orig, smooth, Gh, Qh, msk, out);
}